// Round 3
// baseline (458.969 us; speedup 1.0000x reference)
//
#include <hip/hip_runtime.h>
#include <cstdint>
#include <cstddef>

#define NB 32
#define NKEYS 4096
#define DQ 512      // Q_SIZE == K_SIZE
#define HDIM 256

#define BM 64
#define BK 64
#define LDK 72      // padded LDS stride (bf16 elems): 144 B, breaks 128B-stride conflicts

typedef __attribute__((ext_vector_type(8))) short bf16x8;
typedef __attribute__((ext_vector_type(4))) float f32x4;

__device__ __forceinline__ unsigned short f2bf(float f) {
    union { float f; unsigned u; } v; v.f = f;
    unsigned r = v.u + 0x7FFFu + ((v.u >> 16) & 1u);   // round-to-nearest-even
    return (unsigned short)(r >> 16);
}

__device__ __forceinline__ float tanh_fast(float x) {
    // tanh(x) = 1 - 2/(exp(2x)+1); saturates correctly for |x| large
    float e = __expf(2.0f * x);
    return 1.0f - 2.0f / (e + 1.0f);
}

// ---- Kernel 0a: W_k [512][256] f32 -> WkT [256][512] bf16 (transpose + cvt) ----
__global__ void k_prep_wkT(const float* __restrict__ Wk, unsigned short* __restrict__ WkT) {
    int idx = blockIdx.x * 256 + threadIdx.x;     // 512 blocks x 256 thr = 131072
    int d = idx >> 8, h = idx & 255;
    WkT[h * DQ + d] = f2bf(Wk[idx]);
}

// ---- Kernel 0b: qp[b][h] = sum_d queries[b][d] * Wq[d][h]  (fp32, exact) ----
__global__ void k_qproj(const float* __restrict__ q, const float* __restrict__ Wq,
                        float* __restrict__ qp) {
    __shared__ float qrow[DQ];
    __shared__ float part[512];
    const int b = blockIdx.x;
    const int tid = threadIdx.x;                  // 512 threads
    qrow[tid] = q[b * DQ + tid];
    __syncthreads();
    const int h = tid & 255;
    const int half = tid >> 8;                    // 0..1
    float s = 0.f;
    const int d0 = half * 256;
    #pragma unroll 8
    for (int d = d0; d < d0 + 256; ++d)
        s += qrow[d] * Wq[d * HDIM + h];
    part[tid] = s;
    __syncthreads();
    if (tid < 256) qp[b * HDIM + tid] = part[tid] + part[tid + 256];
}

// ---- Kernel 1: fused  k = keys @ W_k (bf16 MFMA, fp32 acc)  ->  tanh-reduce -> scores ----
// block: 256 threads (4 waves), tile BM=64 rows x all 256 cols, BK=64 K-chunks
__global__ __launch_bounds__(256, 3) void k_scores(
        const float* __restrict__ keys, const unsigned short* __restrict__ WkT,
        const float* __restrict__ qp, const float* __restrict__ wv,
        float* __restrict__ scores) {
    __shared__ unsigned short As[BM * LDK];       //  9.2 KB
    __shared__ unsigned short Bs[HDIM * LDK];     // 36.9 KB
    __shared__ float s_rows[BM];

    const int tid = threadIdx.x;
    const int lane = tid & 63;
    const int wid = tid >> 6;                     // wave col: 0..3 (cols wid*64..+63)
    const int row0 = blockIdx.x * BM;             // global key-row base
    const int b = row0 >> 12;                     // row0 / 4096 (block never spans batches)
    const int l15 = lane & 15;
    const int l4  = lane >> 4;

    f32x4 acc[4][4];
    #pragma unroll
    for (int i = 0; i < 4; ++i)
        #pragma unroll
        for (int j = 0; j < 4; ++j)
            acc[i][j] = (f32x4){0.f, 0.f, 0.f, 0.f};

    for (int kt = 0; kt < DQ; kt += BK) {
        // stage A: 64 rows x 16 float4 -> bf16  (coalesced: 16 thr x 16B per row)
        #pragma unroll
        for (int i = 0; i < 4; ++i) {
            int idx = tid + i * 256;              // 0..1023
            int row = idx >> 4, q4 = idx & 15;
            const float4 v = *reinterpret_cast<const float4*>(
                &keys[(size_t)(row0 + row) * DQ + kt + q4 * 4]);
            ushort4 h4;
            h4.x = f2bf(v.x); h4.y = f2bf(v.y); h4.z = f2bf(v.z); h4.w = f2bf(v.w);
            *reinterpret_cast<ushort4*>(&As[row * LDK + q4 * 4]) = h4;
        }
        // stage B: copy WkT[col][kt..kt+63] -> Bs[col][0..63]   (bf16, 16B chunks)
        #pragma unroll
        for (int i = 0; i < 8; ++i) {
            int idx = tid + i * 256;              // 0..2047
            int col = idx >> 3, j = idx & 7;
            const uint4 v = *reinterpret_cast<const uint4*>(
                &WkT[(size_t)col * DQ + kt + j * 8]);
            *reinterpret_cast<uint4*>(&Bs[col * LDK + j * 8]) = v;
        }
        __syncthreads();
        #pragma unroll
        for (int kk = 0; kk < BK; kk += 32) {
            bf16x8 a[4], bb[4];
            const int kb = kk + l4 * 8;
            #pragma unroll
            for (int i = 0; i < 4; ++i)
                a[i] = *reinterpret_cast<const bf16x8*>(&As[(i * 16 + l15) * LDK + kb]);
            #pragma unroll
            for (int j = 0; j < 4; ++j)
                bb[j] = *reinterpret_cast<const bf16x8*>(&Bs[(wid * 64 + j * 16 + l15) * LDK + kb]);
            #pragma unroll
            for (int i = 0; i < 4; ++i)
                #pragma unroll
                for (int j = 0; j < 4; ++j)
                    acc[i][j] = __builtin_amdgcn_mfma_f32_16x16x32_bf16(
                        a[i], bb[j], acc[i][j], 0, 0, 0);
        }
        __syncthreads();
    }

    // epilogue: s[row] = sum_h tanh(C[row][h] + q[b][h]) * wv[h]
    if (tid < BM) s_rows[tid] = 0.f;
    __syncthreads();

    float qv[4], wvv[4];
    #pragma unroll
    for (int j = 0; j < 4; ++j) {
        int col = wid * 64 + j * 16 + l15;        // C/D: col = lane&15 (+16*j frag)
        qv[j]  = qp[b * HDIM + col];
        wvv[j] = wv[col];
    }
    #pragma unroll
    for (int i = 0; i < 4; ++i) {
        #pragma unroll
        for (int r = 0; r < 4; ++r) {
            float p = 0.f;
            #pragma unroll
            for (int j = 0; j < 4; ++j) {
                float x = acc[i][j][r] + qv[j];
                p += tanh_fast(x) * wvv[j];
            }
            // reduce across the 16 col-lanes of this row
            p += __shfl_xor(p, 1);
            p += __shfl_xor(p, 2);
            p += __shfl_xor(p, 4);
            p += __shfl_xor(p, 8);
            if (l15 == 0)                         // C/D: row = (lane>>4)*4 + reg
                atomicAdd(&s_rows[i * 16 + l4 * 4 + r], p);
        }
    }
    __syncthreads();
    if (tid < BM) scores[row0 + tid] = s_rows[tid];
}

// ---- Kernel 2: per-batch softmax over 4096 scores, multiply by values ----
__global__ void k_softmax(const float* __restrict__ scores, const float* __restrict__ values,
                          float* __restrict__ out) {
    __shared__ float red[8];
    const int b = blockIdx.x, tid = threadIdx.x;  // 256 threads
    const float* s = scores + b * NKEYS;
    float v[16];
    float m = -1e30f;
    #pragma unroll
    for (int i = 0; i < 16; ++i) { v[i] = s[tid + i * 256]; m = fmaxf(m, v[i]); }
    #pragma unroll
    for (int off = 1; off < 64; off <<= 1) m = fmaxf(m, __shfl_xor(m, off));
    const int wid = tid >> 6;
    if ((tid & 63) == 0) red[wid] = m;
    __syncthreads();
    m = fmaxf(fmaxf(red[0], red[1]), fmaxf(red[2], red[3]));
    float sum = 0.f;
    #pragma unroll
    for (int i = 0; i < 16; ++i) { v[i] = __expf(v[i] - m); sum += v[i]; }
    #pragma unroll
    for (int off = 1; off < 64; off <<= 1) sum += __shfl_xor(sum, off);
    if ((tid & 63) == 0) red[4 + wid] = sum;
    __syncthreads();
    sum = red[4] + red[5] + red[6] + red[7];
    const float inv = 1.0f / sum;
    #pragma unroll
    for (int i = 0; i < 16; ++i) {
        int n = tid + i * 256;
        out[b * NKEYS + n] = v[i] * inv * values[b * NKEYS + n];
    }
}

extern "C" void kernel_launch(void* const* d_in, const int* in_sizes, int n_in,
                              void* d_out, int out_size, void* d_ws, size_t ws_size,
                              hipStream_t stream) {
    const float* queries = (const float*)d_in[0];
    const float* keys    = (const float*)d_in[1];
    const float* values  = (const float*)d_in[2];
    const float* Wq      = (const float*)d_in[3];
    const float* Wk      = (const float*)d_in[4];
    const float* wv      = (const float*)d_in[5];
    float* out = (float*)d_out;

    char* ws = (char*)d_ws;
    float* scores        = (float*)ws;                              // 131072 f32 = 512 KB
    float* qp            = (float*)(ws + 131072 * 4);               //   8192 f32 =  32 KB
    unsigned short* WkT  = (unsigned short*)(ws + 131072 * 4 + 8192 * 4); // 131072 bf16 = 256 KB

    hipLaunchKernelGGL(k_prep_wkT, dim3(512), dim3(256), 0, stream, Wk, WkT);
    hipLaunchKernelGGL(k_qproj,    dim3(NB),  dim3(512), 0, stream, queries, Wq, qp);
    hipLaunchKernelGGL(k_scores,   dim3(NB * NKEYS / BM), dim3(256), 0, stream,
                       keys, WkT, qp, wv, scores);
    hipLaunchKernelGGL(k_softmax,  dim3(NB),  dim3(256), 0, stream, scores, values, out);
}

// Round 4
// 414.551 us; speedup vs baseline: 1.1071x; 1.1071x over previous
//
#include <hip/hip_runtime.h>
#include <cstdint>
#include <cstddef>

#define NB 32
#define NKEYS 4096
#define DQ 512      // Q_SIZE == K_SIZE
#define HDIM 256

#define BM 64
#define BK 64

typedef __attribute__((ext_vector_type(8))) short bf16x8;
typedef __attribute__((ext_vector_type(4))) float f32x4;

typedef __attribute__((address_space(1))) const unsigned int g_u32;
typedef __attribute__((address_space(3))) unsigned int l_u32;

__device__ __forceinline__ unsigned short f2bf(float f) {
    union { float f; unsigned u; } v; v.f = f;
    unsigned r = v.u + 0x7FFFu + ((v.u >> 16) & 1u);   // round-to-nearest-even
    return (unsigned short)(r >> 16);
}

__device__ __forceinline__ float tanh_fast(float x) {
    float e = __expf(2.0f * x);
    return 1.0f - 2.0f / (e + 1.0f);
}

// async global->LDS, 16B per lane; LDS dest = wave-uniform base + lane*16 (linear)
__device__ __forceinline__ void gload_lds16(const void* g, void* l) {
    __builtin_amdgcn_global_load_lds((g_u32*)g, (l_u32*)l, 16, 0, 0);
}

// ---- Kernel 0a: W_k [512][256] f32 -> WkT [256][512] bf16, coalesced via LDS tile ----
__global__ void k_prep_wkT(const float* __restrict__ Wk, unsigned short* __restrict__ WkT) {
    __shared__ unsigned short t[64][65];
    const int tid = threadIdx.x;                  // 256
    const int dt = (blockIdx.x >> 2) << 6;        // 8 d-tiles
    const int ht = (blockIdx.x & 3) << 6;         // 4 h-tiles
    #pragma unroll
    for (int i = 0; i < 16; ++i) {
        int idx = tid + i * 256;                  // 0..4095
        int d = idx >> 6, h = idx & 63;           // read coalesced over h
        t[d][h] = f2bf(Wk[(size_t)(dt + d) * HDIM + ht + h]);
    }
    __syncthreads();
    #pragma unroll
    for (int i = 0; i < 16; ++i) {
        int idx = tid + i * 256;
        int h = idx >> 6, d = idx & 63;           // write coalesced over d
        WkT[(size_t)(ht + h) * DQ + dt + d] = t[d][h];
    }
}

// ---- Kernel 0b: qp[b][h] = sum_d queries[b][d] * Wq[d][h]  (fp32, exact) ----
// grid: 32 b x 4 h-quarters = 128 blocks, 256 threads (64 h x 4 d-quarters)
__global__ void k_qproj(const float* __restrict__ q, const float* __restrict__ Wq,
                        float* __restrict__ qp) {
    __shared__ float qrow[DQ];
    __shared__ float part[256];
    const int blk = blockIdx.x;
    const int b = blk >> 2, hq = blk & 3;
    const int tid = threadIdx.x;                  // 256
    qrow[tid]       = q[b * DQ + tid];
    qrow[tid + 256] = q[b * DQ + tid + 256];
    __syncthreads();
    const int h = (hq << 6) + (tid & 63);
    const int d0 = (tid >> 6) << 7;               // d-quarter base (0,128,256,384)
    float s = 0.f;
    #pragma unroll 4
    for (int d = d0; d < d0 + 128; ++d)
        s += qrow[d] * Wq[d * HDIM + h];
    part[tid] = s;
    __syncthreads();
    if (tid < 64)
        qp[b * HDIM + (hq << 6) + tid] =
            part[tid] + part[tid + 64] + part[tid + 128] + part[tid + 192];
}

// ---- Kernel 1: fused  keys @ W_k (bf16 MFMA) -> tanh-reduce -> scores ----
// 2048 blocks x 256 thr (4 waves), BM=64 rows, all 256 cols, BK=64, double-buffered.
// LDS layout: [row][64] bf16, 128B rows, XOR-swizzled 16B slots: phys = log ^ (row&7).
__global__ __launch_bounds__(256, 2) void k_scores(
        const float* __restrict__ keys, const unsigned short* __restrict__ WkT,
        const float* __restrict__ qp, const float* __restrict__ wv,
        float* __restrict__ scores) {
    __shared__ __align__(16) unsigned short As[2][BM * BK];     // 2 x  8 KB
    __shared__ __align__(16) unsigned short Bs[2][HDIM * BK];   // 2 x 32 KB  (total 80 KB)
    float* s_rows = reinterpret_cast<float*>(&As[0][0]);        // epilogue alias

    const int tid  = threadIdx.x;
    const int lane = tid & 63;
    const int wid  = tid >> 6;                    // wave col-strip 0..3
    const int row0 = blockIdx.x * BM;
    const int b    = row0 >> 12;
    const int l15  = lane & 15;
    const int l4   = lane >> 4;

    // A staging: thread -> 4 float4 (rows ar+16i, 16B chunk ac4)
    const int ar  = tid >> 4;
    const int ac4 = tid & 15;
    const float* aptr[4];
    int awoff[4];
    #pragma unroll
    for (int i = 0; i < 4; ++i) {
        const int row = ar + i * 16;
        aptr[i]  = keys + (size_t)(row0 + row) * DQ + ac4 * 4;
        awoff[i] = row * 128 + (((ac4 >> 1) ^ (row & 7)) << 4) + (ac4 & 1) * 8;
    }
    // B staging: lane -> col = wid*64 + q*8 + (lane>>3); source slot pre-swizzled
    const int bcol = wid * 64 + (lane >> 3);
    const int bsw  = (lane & 7) ^ ((lane >> 3) & 7);
    const unsigned short* bptr = WkT + (size_t)bcol * DQ + bsw * 8;

    // fragment read slot bytes (phys = log ^ (row&7); row&7 == l15&7 for all frags)
    const int r7 = l15 & 7;
    const int asl0 = (l4 ^ r7) << 4;              // kk=0
    const int asl1 = ((4 + l4) ^ r7) << 4;        // kk=1

    f32x4 acc[4][4];
    #pragma unroll
    for (int i = 0; i < 4; ++i)
        #pragma unroll
        for (int j = 0; j < 4; ++j)
            acc[i][j] = (f32x4){0.f, 0.f, 0.f, 0.f};

    float4 rA[4];

    // prologue: stage kt=0 into buffer 0
    #pragma unroll
    for (int i = 0; i < 4; ++i) rA[i] = *reinterpret_cast<const float4*>(aptr[i]);
    #pragma unroll
    for (int q = 0; q < 8; ++q)
        gload_lds16(bptr + q * (8 * DQ), &Bs[0][(wid * 64 + q * 8) * BK]);
    #pragma unroll
    for (int i = 0; i < 4; ++i) {
        ushort4 h4;
        h4.x = f2bf(rA[i].x); h4.y = f2bf(rA[i].y); h4.z = f2bf(rA[i].z); h4.w = f2bf(rA[i].w);
        *reinterpret_cast<ushort4*>(reinterpret_cast<char*>(&As[0][0]) + awoff[i]) = h4;
    }
    __syncthreads();

    #pragma unroll
    for (int kt = 0; kt < 8; ++kt) {
        const int cur = kt & 1;
        if (kt < 7) {
            // issue next tile's loads BEFORE compute (latency hides under MFMA)
            #pragma unroll
            for (int i = 0; i < 4; ++i)
                rA[i] = *reinterpret_cast<const float4*>(aptr[i] + (kt + 1) * BK);
            #pragma unroll
            for (int q = 0; q < 8; ++q)
                gload_lds16(bptr + (kt + 1) * BK + q * (8 * DQ),
                            &Bs[cur ^ 1][(wid * 64 + q * 8) * BK]);
        }
        const char* Ab = reinterpret_cast<const char*>(&As[cur][0]);
        const char* Bb = reinterpret_cast<const char*>(&Bs[cur][0]);
        #pragma unroll
        for (int kk = 0; kk < 2; ++kk) {
            const int sl = kk ? asl1 : asl0;
            bf16x8 a[4], bb[4];
            #pragma unroll
            for (int i = 0; i < 4; ++i)
                a[i] = *reinterpret_cast<const bf16x8*>(Ab + (i * 16 + l15) * 128 + sl);
            #pragma unroll
            for (int j = 0; j < 4; ++j)
                bb[j] = *reinterpret_cast<const bf16x8*>(Bb + (wid * 64 + j * 16 + l15) * 128 + sl);
            #pragma unroll
            for (int i = 0; i < 4; ++i)
                #pragma unroll
                for (int j = 0; j < 4; ++j)
                    acc[i][j] = __builtin_amdgcn_mfma_f32_16x16x32_bf16(
                        a[i], bb[j], acc[i][j], 0, 0, 0);
        }
        __syncthreads();               // done reading buf cur; drains issued loads
        if (kt < 7) {
            #pragma unroll
            for (int i = 0; i < 4; ++i) {
                ushort4 h4;
                h4.x = f2bf(rA[i].x); h4.y = f2bf(rA[i].y);
                h4.z = f2bf(rA[i].z); h4.w = f2bf(rA[i].w);
                *reinterpret_cast<ushort4*>(
                    reinterpret_cast<char*>(&As[cur ^ 1][0]) + awoff[i]) = h4;
            }
            __syncthreads();           // next buffers ready
        }
    }

    // epilogue: s[row] = sum_h tanh(C[row][h] + qp[b][h]) * wv[h]   (verified layout)
    if (tid < BM) s_rows[tid] = 0.f;
    __syncthreads();

    float qv[4], wvv[4];
    #pragma unroll
    for (int j = 0; j < 4; ++j) {
        int col = wid * 64 + j * 16 + l15;        // C/D: col = lane&15 (+16*j frag)
        qv[j]  = qp[b * HDIM + col];
        wvv[j] = wv[col];
    }
    #pragma unroll
    for (int i = 0; i < 4; ++i) {
        #pragma unroll
        for (int r = 0; r < 4; ++r) {
            float p = 0.f;
            #pragma unroll
            for (int j = 0; j < 4; ++j) {
                float x = acc[i][j][r] + qv[j];
                p += tanh_fast(x) * wvv[j];
            }
            p += __shfl_xor(p, 1);
            p += __shfl_xor(p, 2);
            p += __shfl_xor(p, 4);
            p += __shfl_xor(p, 8);
            if (l15 == 0)                         // C/D: row = (lane>>4)*4 + reg
                atomicAdd(&s_rows[i * 16 + l4 * 4 + r], p);
        }
    }
    __syncthreads();
    if (tid < BM) scores[row0 + tid] = s_rows[tid];
}

// ---- Kernel 2: per-batch softmax over 4096 scores, multiply by values ----
__global__ void k_softmax(const float* __restrict__ scores, const float* __restrict__ values,
                          float* __restrict__ out) {
    __shared__ float red[32];
    const int b = blockIdx.x, tid = threadIdx.x;  // 1024 threads, 16 waves
    const float* s = scores + b * NKEYS;
    float v[4];
    float m = -1e30f;
    #pragma unroll
    for (int i = 0; i < 4; ++i) { v[i] = s[tid + i * 1024]; m = fmaxf(m, v[i]); }
    #pragma unroll
    for (int off = 1; off < 64; off <<= 1) m = fmaxf(m, __shfl_xor(m, off));
    const int w = tid >> 6;
    if ((tid & 63) == 0) red[w] = m;
    __syncthreads();
    m = red[0];
    #pragma unroll
    for (int i = 1; i < 16; ++i) m = fmaxf(m, red[i]);
    float sum = 0.f;
    #pragma unroll
    for (int i = 0; i < 4; ++i) { v[i] = __expf(v[i] - m); sum += v[i]; }
    #pragma unroll
    for (int off = 1; off < 64; off <<= 1) sum += __shfl_xor(sum, off);
    if ((tid & 63) == 0) red[16 + w] = sum;
    __syncthreads();
    sum = red[16];
    #pragma unroll
    for (int i = 1; i < 16; ++i) sum += red[16 + i];
    const float inv = 1.0f / sum;
    #pragma unroll
    for (int i = 0; i < 4; ++i) {
        int n = tid + i * 1024;
        out[b * NKEYS + n] = v[i] * inv * values[b * NKEYS + n];
    }
}

extern "C" void kernel_launch(void* const* d_in, const int* in_sizes, int n_in,
                              void* d_out, int out_size, void* d_ws, size_t ws_size,
                              hipStream_t stream) {
    const float* queries = (const float*)d_in[0];
    const float* keys    = (const float*)d_in[1];
    const float* values  = (const float*)d_in[2];
    const float* Wq      = (const float*)d_in[3];
    const float* Wk      = (const float*)d_in[4];
    const float* wv      = (const float*)d_in[5];
    float* out = (float*)d_out;

    char* ws = (char*)d_ws;
    float* scores        = (float*)ws;                                   // 512 KB
    float* qp            = (float*)(ws + 131072 * 4);                    //  32 KB
    unsigned short* WkT  = (unsigned short*)(ws + 131072 * 4 + 8192 * 4);// 256 KB

    hipLaunchKernelGGL(k_prep_wkT, dim3(32),   dim3(256),  0, stream, Wk, WkT);
    hipLaunchKernelGGL(k_qproj,    dim3(128),  dim3(256),  0, stream, queries, Wq, qp);
    hipLaunchKernelGGL(k_scores,   dim3(NB * NKEYS / BM), dim3(256), 0, stream,
                       keys, WkT, qp, wv, scores);
    hipLaunchKernelGGL(k_softmax,  dim3(NB),   dim3(1024), 0, stream, scores, values, out);
}

// Round 10
// 398.860 us; speedup vs baseline: 1.1507x; 1.0393x over previous
//
#include <hip/hip_runtime.h>
#include <cstdint>
#include <cstddef>

#define NB 32
#define NKEYS 4096
#define DQ 512      // Q_SIZE == K_SIZE
#define HDIM 256

#define BM 64
#define BK 64

typedef __attribute__((ext_vector_type(8))) short bf16x8;
typedef __attribute__((ext_vector_type(4))) float f32x4;

typedef __attribute__((address_space(1))) const unsigned int g_u32;
typedef __attribute__((address_space(3))) unsigned int l_u32;

__device__ __forceinline__ unsigned short f2bf(float f) {
    union { float f; unsigned u; } v; v.f = f;
    unsigned r = v.u + 0x7FFFu + ((v.u >> 16) & 1u);   // round-to-nearest-even
    return (unsigned short)(r >> 16);
}

__device__ __forceinline__ float tanh_fast(float x) {
    float e = __expf(2.0f * x);
    return 1.0f - 2.0f / (e + 1.0f);
}

// async global->LDS, 16B per lane; LDS dest = wave-uniform base + lane*16 (linear)
__device__ __forceinline__ void gload_lds16(const void* g, void* l) {
    __builtin_amdgcn_global_load_lds((g_u32*)g, (l_u32*)l, 16, 0, 0);
}

// ---- Kernel 0a: W_k [512][256] f32 -> WkT [256][512] bf16, coalesced via LDS tile ----
__global__ void k_prep_wkT(const float* __restrict__ Wk, unsigned short* __restrict__ WkT) {
    __shared__ unsigned short t[64][65];
    const int tid = threadIdx.x;                  // 256
    const int dt = (blockIdx.x >> 2) << 6;        // 8 d-tiles
    const int ht = (blockIdx.x & 3) << 6;         // 4 h-tiles
    #pragma unroll
    for (int i = 0; i < 16; ++i) {
        int idx = tid + i * 256;                  // 0..4095
        int d = idx >> 6, h = idx & 63;           // read coalesced over h
        t[d][h] = f2bf(Wk[(size_t)(dt + d) * HDIM + ht + h]);
    }
    __syncthreads();
    #pragma unroll
    for (int i = 0; i < 16; ++i) {
        int idx = tid + i * 256;
        int h = idx >> 6, d = idx & 63;           // write coalesced over d
        WkT[(size_t)(ht + h) * DQ + dt + d] = t[d][h];
    }
}

// ---- Kernel 0b: qp[b][h] = sum_d queries[b][d] * Wq[d][h]  (fp32, exact) ----
// grid: 32 b x 4 h-quarters = 128 blocks, 256 threads (64 h x 4 d-quarters)
__global__ void k_qproj(const float* __restrict__ q, const float* __restrict__ Wq,
                        float* __restrict__ qp) {
    __shared__ float qrow[DQ];
    __shared__ float part[256];
    const int blk = blockIdx.x;
    const int b = blk >> 2, hq = blk & 3;
    const int tid = threadIdx.x;                  // 256
    qrow[tid]       = q[b * DQ + tid];
    qrow[tid + 256] = q[b * DQ + tid + 256];
    __syncthreads();
    const int h = (hq << 6) + (tid & 63);
    const int d0 = (tid >> 6) << 7;               // d-quarter base (0,128,256,384)
    float s = 0.f;
    #pragma unroll 4
    for (int d = d0; d < d0 + 128; ++d)
        s += qrow[d] * Wq[d * HDIM + h];
    part[tid] = s;
    __syncthreads();
    if (tid < 64)
        qp[b * HDIM + (hq << 6) + tid] =
            part[tid] + part[tid + 64] + part[tid + 128] + part[tid + 192];
}

// ---- Kernel 1: fused  keys @ W_k (bf16 MFMA) -> tanh-reduce -> scores ----
// 2048 blocks x 256 thr (4 waves), BM=64 rows, all 256 cols, BK=64.
// Single raw barrier per K-step + counted vmcnt: keys loads for kt+2 stay in
// flight across the barrier (the round-4 __syncthreads drained vmcnt(0) every
// half-step, exposing full HBM latency per iteration).
// LDS layout: [row][64] bf16, 128B rows, XOR-swizzled 16B slots: phys = log ^ (row&7).
__global__ __launch_bounds__(256, 2) void k_scores(
        const float* __restrict__ keys, const unsigned short* __restrict__ WkT,
        const float* __restrict__ qp, const float* __restrict__ wv,
        float* __restrict__ scores) {
    __shared__ __align__(16) unsigned short As[2][BM * BK];     // 2 x  8 KB
    __shared__ __align__(16) unsigned short Bs[2][HDIM * BK];   // 2 x 32 KB  (total 80 KB)
    float* s_rows = reinterpret_cast<float*>(&As[0][0]);        // epilogue alias (As dead then)

    const int tid  = threadIdx.x;
    const int lane = tid & 63;
    const int wid  = tid >> 6;                    // wave col-strip 0..3
    const int row0 = blockIdx.x * BM;
    const int b    = row0 >> 12;
    const int l15  = lane & 15;
    const int l4   = lane >> 4;

    // A staging: thread -> 4 float4 (rows ar+16i, 16B chunk ac4)
    const int ar  = tid >> 4;
    const int ac4 = tid & 15;
    const float* aptr[4];
    int awoff[4];
    #pragma unroll
    for (int i = 0; i < 4; ++i) {
        const int row = ar + i * 16;
        aptr[i]  = keys + (size_t)(row0 + row) * DQ + ac4 * 4;
        awoff[i] = row * 128 + (((ac4 >> 1) ^ (row & 7)) << 4) + (ac4 & 1) * 8;
    }
    // B staging: lane -> col = wid*64 + q*8 + (lane>>3); source slot pre-swizzled
    const int bcol = wid * 64 + (lane >> 3);
    const int bsw  = (lane & 7) ^ ((lane >> 3) & 7);
    const unsigned short* bptr = WkT + (size_t)bcol * DQ + bsw * 8;

    // fragment read slot bytes (phys = log ^ (row&7); row&7 == l15&7 for all frags)
    const int r7 = l15 & 7;
    const int asl0 = (l4 ^ r7) << 4;              // kk=0
    const int asl1 = ((4 + l4) ^ r7) << 4;        // kk=1

    f32x4 acc[4][4];
    #pragma unroll
    for (int i = 0; i < 4; ++i)
        #pragma unroll
        for (int j = 0; j < 4; ++j)
            acc[i][j] = (f32x4){0.f, 0.f, 0.f, 0.f};

    float4 rA1[4], rA2[4];                        // tiles kt+1: odd->rA1, even->rA2

    // ---- prologue: stage tile 0, issue A(1) ----
    #pragma unroll
    for (int q = 0; q < 8; ++q)
        gload_lds16(bptr + q * (8 * DQ), &Bs[0][(wid * 64 + q * 8) * BK]);
    {
        float4 t0[4];
        #pragma unroll
        for (int i = 0; i < 4; ++i) t0[i] = *reinterpret_cast<const float4*>(aptr[i]);
        #pragma unroll
        for (int i = 0; i < 4; ++i) {
            ushort4 h4;
            h4.x = f2bf(t0[i].x); h4.y = f2bf(t0[i].y);
            h4.z = f2bf(t0[i].z); h4.w = f2bf(t0[i].w);
            *reinterpret_cast<ushort4*>(reinterpret_cast<char*>(&As[0][0]) + awoff[i]) = h4;
        }
    }
    asm volatile("s_waitcnt vmcnt(0)" ::: "memory");   // B(0) landed
    asm volatile("s_waitcnt lgkmcnt(0)" ::: "memory");
    __builtin_amdgcn_s_barrier();
    #pragma unroll
    for (int i = 0; i < 4; ++i)                        // issue A(1) (in flight)
        rA1[i] = *reinterpret_cast<const float4*>(aptr[i] + 1 * BK);

    // ---- main loop: one barrier per K-step, counted vmcnt ----
    #pragma unroll
    for (int kt = 0; kt < 8; ++kt) {
        const int cur = kt & 1, nxt = cur ^ 1;
        if (kt < 7) {
            #pragma unroll
            for (int q = 0; q < 8; ++q)
                gload_lds16(bptr + (kt + 1) * BK + q * (8 * DQ),
                            &Bs[nxt][(wid * 64 + q * 8) * BK]);
        }
        const char* Ab = reinterpret_cast<const char*>(&As[cur][0]);
        const char* Bb = reinterpret_cast<const char*>(&Bs[cur][0]);
        #pragma unroll
        for (int kk = 0; kk < 2; ++kk) {
            const int sl = kk ? asl1 : asl0;
            bf16x8 a[4], bb[4];
            #pragma unroll
            for (int i = 0; i < 4; ++i)
                a[i] = *reinterpret_cast<const bf16x8*>(Ab + (i * 16 + l15) * 128 + sl);
            #pragma unroll
            for (int j = 0; j < 4; ++j)
                bb[j] = *reinterpret_cast<const bf16x8*>(Bb + (wid * 64 + j * 16 + l15) * 128 + sl);
            __builtin_amdgcn_s_setprio(1);
            #pragma unroll
            for (int i = 0; i < 4; ++i)
                #pragma unroll
                for (int j = 0; j < 4; ++j)
                    acc[i][j] = __builtin_amdgcn_mfma_f32_16x16x32_bf16(
                        a[i], bb[j], acc[i][j], 0, 0, 0);
            __builtin_amdgcn_s_setprio(0);
        }
        if (kt < 7) {
            // cvt A(kt+1) (compiler auto-waits its loads, issued one iter ago)
            #pragma unroll
            for (int i = 0; i < 4; ++i) {
                const float4 v = (kt & 1) ? rA2[i] : rA1[i];
                ushort4 h4;
                h4.x = f2bf(v.x); h4.y = f2bf(v.y); h4.z = f2bf(v.z); h4.w = f2bf(v.w);
                *reinterpret_cast<ushort4*>(
                    reinterpret_cast<char*>(&As[nxt][0]) + awoff[i]) = h4;
            }
            if (kt < 6) {
                #pragma unroll
                for (int i = 0; i < 4; ++i) {      // issue A(kt+2)
                    const float4 v = *reinterpret_cast<const float4*>(aptr[i] + (kt + 2) * BK);
                    if (kt & 1) rA1[i] = v; else rA2[i] = v;
                }
                // B(kt+1) landed; A(kt+2)'s 4 loads stay in flight across barrier
                asm volatile("s_waitcnt vmcnt(4)" ::: "memory");
            } else {
                asm volatile("s_waitcnt vmcnt(0)" ::: "memory");
            }
            asm volatile("s_waitcnt lgkmcnt(0)" ::: "memory");
            __builtin_amdgcn_s_barrier();
        }
    }

    // epilogue: s[row] = sum_h tanh(C[row][h] + qp[b][h]) * wv[h]   (verified layout)
    if (tid < BM) s_rows[tid] = 0.f;
    __syncthreads();

    float qv[4], wvv[4];
    #pragma unroll
    for (int j = 0; j < 4; ++j) {
        int col = wid * 64 + j * 16 + l15;        // C/D: col = lane&15 (+16*j frag)
        qv[j]  = qp[b * HDIM + col];
        wvv[j] = wv[col];
    }
    #pragma unroll
    for (int i = 0; i < 4; ++i) {
        #pragma unroll
        for (int r = 0; r < 4; ++r) {
            float p = 0.f;
            #pragma unroll
            for (int j = 0; j < 4; ++j) {
                float x = acc[i][j][r] + qv[j];
                p += tanh_fast(x) * wvv[j];
            }
            p += __shfl_xor(p, 1);
            p += __shfl_xor(p, 2);
            p += __shfl_xor(p, 4);
            p += __shfl_xor(p, 8);
            if (l15 == 0)                         // C/D: row = (lane>>4)*4 + reg
                atomicAdd(&s_rows[i * 16 + l4 * 4 + r], p);
        }
    }
    __syncthreads();
    if (tid < BM) scores[row0 + tid] = s_rows[tid];
}

// ---- Kernel 2: per-batch softmax over 4096 scores, multiply by values ----
__global__ void k_softmax(const float* __restrict__ scores, const float* __restrict__ values,
                          float* __restrict__ out) {
    __shared__ float red[32];
    const int b = blockIdx.x, tid = threadIdx.x;  // 1024 threads, 16 waves
    const float* s = scores + b * NKEYS;
    float v[4];
    float m = -1e30f;
    #pragma unroll
    for (int i = 0; i < 4; ++i) { v[i] = s[tid + i * 1024]; m = fmaxf(m, v[i]); }
    #pragma unroll
    for (int off = 1; off < 64; off <<= 1) m = fmaxf(m, __shfl_xor(m, off));
    const int w = tid >> 6;
    if ((tid & 63) == 0) red[w] = m;
    __syncthreads();
    m = red[0];
    #pragma unroll
    for (int i = 1; i < 16; ++i) m = fmaxf(m, red[i]);
    float sum = 0.f;
    #pragma unroll
    for (int i = 0; i < 4; ++i) { v[i] = __expf(v[i] - m); sum += v[i]; }
    #pragma unroll
    for (int off = 1; off < 64; off <<= 1) sum += __shfl_xor(sum, off);
    if ((tid & 63) == 0) red[16 + w] = sum;
    __syncthreads();
    sum = red[16];
    #pragma unroll
    for (int i = 1; i < 16; ++i) sum += red[16 + i];
    const float inv = 1.0f / sum;
    #pragma unroll
    for (int i = 0; i < 4; ++i) {
        int n = tid + i * 1024;
        out[b * NKEYS + n] = v[i] * inv * values[b * NKEYS + n];
    }
}

extern "C" void kernel_launch(void* const* d_in, const int* in_sizes, int n_in,
                              void* d_out, int out_size, void* d_ws, size_t ws_size,
                              hipStream_t stream) {
    const float* queries = (const float*)d_in[0];
    const float* keys    = (const float*)d_in[1];
    const float* values  = (const float*)d_in[2];
    const float* Wq      = (const float*)d_in[3];
    const float* Wk      = (const float*)d_in[4];
    const float* wv      = (const float*)d_in[5];
    float* out = (float*)d_out;

    char* ws = (char*)d_ws;
    float* scores        = (float*)ws;                                   // 512 KB
    float* qp            = (float*)(ws + 131072 * 4);                    //  32 KB
    unsigned short* WkT  = (unsigned short*)(ws + 131072 * 4 + 8192 * 4);// 256 KB

    hipLaunchKernelGGL(k_prep_wkT, dim3(32),   dim3(256),  0, stream, Wk, WkT);
    hipLaunchKernelGGL(k_qproj,    dim3(128),  dim3(256),  0, stream, queries, Wq, qp);
    hipLaunchKernelGGL(k_scores,   dim3(NB * NKEYS / BM), dim3(256), 0, stream,
                       keys, WkT, qp, wv, scores);
    hipLaunchKernelGGL(k_softmax,  dim3(NB),   dim3(1024), 0, stream, scores, values, out);
}

// Round 11
// 396.134 us; speedup vs baseline: 1.1586x; 1.0069x over previous
//
#include <hip/hip_runtime.h>
#include <cstdint>
#include <cstddef>

#define NB 32
#define NKEYS 4096
#define DQ 512      // Q_SIZE == K_SIZE
#define HDIM 256

#define BM 64
#define BK 64

typedef __attribute__((ext_vector_type(8))) short bf16x8;
typedef __attribute__((ext_vector_type(4))) float f32x4;

typedef __attribute__((address_space(1))) const unsigned int g_u32;
typedef __attribute__((address_space(3))) unsigned int l_u32;

__device__ __forceinline__ unsigned short f2bf(float f) {
    union { float f; unsigned u; } v; v.f = f;
    unsigned r = v.u + 0x7FFFu + ((v.u >> 16) & 1u);   // round-to-nearest-even
    return (unsigned short)(r >> 16);
}

__device__ __forceinline__ float tanh_fast(float x) {
    float e = __expf(2.0f * x);
    return 1.0f - 2.0f / (e + 1.0f);
}

// async global->LDS, 16B per lane; LDS dest = wave-uniform base + lane*16 (linear)
__device__ __forceinline__ void gload_lds16(const void* g, void* l) {
    __builtin_amdgcn_global_load_lds((g_u32*)g, (l_u32*)l, 16, 0, 0);
}

// ---- Kernel 0a: W_k [512][256] f32 -> WkT [256][512] bf16, coalesced via LDS tile ----
__global__ void k_prep_wkT(const float* __restrict__ Wk, unsigned short* __restrict__ WkT) {
    __shared__ unsigned short t[64][65];
    const int tid = threadIdx.x;                  // 256
    const int dt = (blockIdx.x >> 2) << 6;        // 8 d-tiles
    const int ht = (blockIdx.x & 3) << 6;         // 4 h-tiles
    #pragma unroll
    for (int i = 0; i < 16; ++i) {
        int idx = tid + i * 256;                  // 0..4095
        int d = idx >> 6, h = idx & 63;           // read coalesced over h
        t[d][h] = f2bf(Wk[(size_t)(dt + d) * HDIM + ht + h]);
    }
    __syncthreads();
    #pragma unroll
    for (int i = 0; i < 16; ++i) {
        int idx = tid + i * 256;
        int h = idx >> 6, d = idx & 63;           // write coalesced over d
        WkT[(size_t)(ht + h) * DQ + dt + d] = t[d][h];
    }
}

// ---- Kernel 0b: qp[b][h] = sum_d queries[b][d] * Wq[d][h]  (fp32, exact) ----
// grid: 32 b x 4 h-quarters = 128 blocks, 256 threads (64 h x 4 d-quarters)
__global__ void k_qproj(const float* __restrict__ q, const float* __restrict__ Wq,
                        float* __restrict__ qp) {
    __shared__ float qrow[DQ];
    __shared__ float part[256];
    const int blk = blockIdx.x;
    const int b = blk >> 2, hq = blk & 3;
    const int tid = threadIdx.x;                  // 256
    qrow[tid]       = q[b * DQ + tid];
    qrow[tid + 256] = q[b * DQ + tid + 256];
    __syncthreads();
    const int h = (hq << 6) + (tid & 63);
    const int d0 = (tid >> 6) << 7;               // d-quarter base (0,128,256,384)
    float s = 0.f;
    #pragma unroll 4
    for (int d = d0; d < d0 + 128; ++d)
        s += qrow[d] * Wq[d * HDIM + h];
    part[tid] = s;
    __syncthreads();
    if (tid < 64)
        qp[b * HDIM + (hq << 6) + tid] =
            part[tid] + part[tid + 64] + part[tid + 128] + part[tid + 192];
}

// ---- Kernel 1: fused  keys @ W_k (bf16 MFMA) -> tanh-reduce -> scores ----
// 2048 blocks x 256 thr (4 waves), BM=64 rows, all 256 cols, BK=64.
// LDS 48 KB -> 3 blocks/CU (was 80 KB / 2 blocks: latency-bound at 8 waves/CU).
// Bs is SINGLE-buffered but wave-private (each wave reads only its own 64-col
// strip), so B staging needs no barrier: wave-order is enforced by lgkmcnt(0)
// before issuing next-tile gload_lds (strip reads drained) and vmcnt(4) at
// iteration top (B(t) landed; 4 = A(t+2) loads issued after B(t+1)'s batch).
// Single barrier per K-step covers only the shared A tile (double-buffered).
// LDS layout: [row][64] bf16, 128B rows, XOR-swizzled 16B slots: phys = log ^ (row&7).
__global__ __launch_bounds__(256, 3) void k_scores(
        const float* __restrict__ keys, const unsigned short* __restrict__ WkT,
        const float* __restrict__ qp, const float* __restrict__ wv,
        float* __restrict__ scores) {
    __shared__ __align__(16) unsigned short As[2][BM * BK];     // 2 x 8 KB
    __shared__ __align__(16) unsigned short Bs[HDIM * BK];      // 32 KB (wave-private strips)
    float* s_rows = reinterpret_cast<float*>(&As[0][0]);        // epilogue alias (As dead then)

    const int tid  = threadIdx.x;
    const int lane = tid & 63;
    const int wid  = tid >> 6;                    // wave col-strip 0..3
    const int row0 = blockIdx.x * BM;
    const int b    = row0 >> 12;
    const int l15  = lane & 15;
    const int l4   = lane >> 4;

    // A staging: thread -> 4 float4 (rows ar+16i, 16B chunk ac4)
    const int ar  = tid >> 4;
    const int ac4 = tid & 15;
    const float* aptr[4];
    int awoff[4];
    #pragma unroll
    for (int i = 0; i < 4; ++i) {
        const int row = ar + i * 16;
        aptr[i]  = keys + (size_t)(row0 + row) * DQ + ac4 * 4;
        awoff[i] = row * 128 + (((ac4 >> 1) ^ (row & 7)) << 4) + (ac4 & 1) * 8;
    }
    // B staging: lane -> col = wid*64 + q*8 + (lane>>3); source slot pre-swizzled
    const int bcol = wid * 64 + (lane >> 3);
    const int bsw  = (lane & 7) ^ ((lane >> 3) & 7);
    const unsigned short* bptr = WkT + (size_t)bcol * DQ + bsw * 8;

    // fragment read slot bytes (phys = log ^ (row&7); row&7 == l15&7 for all frags)
    const int r7 = l15 & 7;
    const int asl0 = (l4 ^ r7) << 4;              // kk=0
    const int asl1 = ((4 + l4) ^ r7) << 4;        // kk=1

    f32x4 acc[4][4];
    #pragma unroll
    for (int i = 0; i < 4; ++i)
        #pragma unroll
        for (int j = 0; j < 4; ++j)
            acc[i][j] = (f32x4){0.f, 0.f, 0.f, 0.f};

    float4 rA1[4], rA2[4];                        // tiles kt+1: odd->rA1, even->rA2

    // ---- prologue: stage tile 0 (B(0) async, A(0) via reg+cvt), then issue A(1) ----
    #pragma unroll
    for (int q = 0; q < 8; ++q)
        gload_lds16(bptr + q * (8 * DQ), &Bs[(wid * 64 + q * 8) * BK]);
    {
        float4 t0[4];
        #pragma unroll
        for (int i = 0; i < 4; ++i) t0[i] = *reinterpret_cast<const float4*>(aptr[i]);
        #pragma unroll
        for (int i = 0; i < 4; ++i) {
            ushort4 h4;
            h4.x = f2bf(t0[i].x); h4.y = f2bf(t0[i].y);
            h4.z = f2bf(t0[i].z); h4.w = f2bf(t0[i].w);
            *reinterpret_cast<ushort4*>(reinterpret_cast<char*>(&As[0][0]) + awoff[i]) = h4;
        }
    }
    asm volatile("s_waitcnt vmcnt(0)" ::: "memory");   // B(0) landed
    asm volatile("s_waitcnt lgkmcnt(0)" ::: "memory"); // As[0] writes visible
    __builtin_amdgcn_s_barrier();
    #pragma unroll
    for (int i = 0; i < 4; ++i)                        // issue A(1) (in flight)
        rA1[i] = *reinterpret_cast<const float4*>(aptr[i] + 1 * BK);

    // ---- main loop: one barrier per K-step (A only); B synced by vmcnt/lgkmcnt ----
    #pragma unroll
    for (int kt = 0; kt < 8; ++kt) {
        const int cur = kt & 1, nxt = cur ^ 1;
        // B(kt) landed: outstanding newer loads = A(kt+1)'s 4 (none at kt=7)
        if (kt == 7) asm volatile("s_waitcnt vmcnt(0)" ::: "memory");
        else         asm volatile("s_waitcnt vmcnt(4)" ::: "memory");

        const char* Ab = reinterpret_cast<const char*>(&As[cur][0]);
        const char* Bb = reinterpret_cast<const char*>(&Bs[0]);

        // kk = 0
        bf16x8 a0[4], b0[4];
        #pragma unroll
        for (int i = 0; i < 4; ++i)
            a0[i] = *reinterpret_cast<const bf16x8*>(Ab + (i * 16 + l15) * 128 + asl0);
        #pragma unroll
        for (int j = 0; j < 4; ++j)
            b0[j] = *reinterpret_cast<const bf16x8*>(Bb + (wid * 64 + j * 16 + l15) * 128 + asl0);
        __builtin_amdgcn_s_setprio(1);
        #pragma unroll
        for (int i = 0; i < 4; ++i)
            #pragma unroll
            for (int j = 0; j < 4; ++j)
                acc[i][j] = __builtin_amdgcn_mfma_f32_16x16x32_bf16(a0[i], b0[j], acc[i][j], 0, 0, 0);
        __builtin_amdgcn_s_setprio(0);

        // kk = 1 reads
        bf16x8 a1[4], b1[4];
        #pragma unroll
        for (int i = 0; i < 4; ++i)
            a1[i] = *reinterpret_cast<const bf16x8*>(Ab + (i * 16 + l15) * 128 + asl1);
        #pragma unroll
        for (int j = 0; j < 4; ++j)
            b1[j] = *reinterpret_cast<const bf16x8*>(Bb + (wid * 64 + j * 16 + l15) * 128 + asl1);

        // all B(kt)/A(kt) strip reads drained -> safe to overwrite B strip
        asm volatile("s_waitcnt lgkmcnt(0)" ::: "memory");
        if (kt < 7) {
            #pragma unroll
            for (int q = 0; q < 8; ++q)
                gload_lds16(bptr + (kt + 1) * BK + q * (8 * DQ),
                            &Bs[(wid * 64 + q * 8) * BK]);
        }
        if (kt < 6) {
            #pragma unroll
            for (int i = 0; i < 4; ++i) {          // issue A(kt+2)
                const float4 v = *reinterpret_cast<const float4*>(aptr[i] + (kt + 2) * BK);
                if (kt & 1) rA1[i] = v; else rA2[i] = v;
            }
        }

        __builtin_amdgcn_s_setprio(1);
        #pragma unroll
        for (int i = 0; i < 4; ++i)
            #pragma unroll
            for (int j = 0; j < 4; ++j)
                acc[i][j] = __builtin_amdgcn_mfma_f32_16x16x32_bf16(a1[i], b1[j], acc[i][j], 0, 0, 0);
        __builtin_amdgcn_s_setprio(0);

        if (kt < 7) {
            // cvt A(kt+1) (compiler auto-waits its loads, issued one iter ago)
            #pragma unroll
            for (int i = 0; i < 4; ++i) {
                const float4 v = (kt & 1) ? rA2[i] : rA1[i];
                ushort4 h4;
                h4.x = f2bf(v.x); h4.y = f2bf(v.y); h4.z = f2bf(v.z); h4.w = f2bf(v.w);
                *reinterpret_cast<ushort4*>(
                    reinterpret_cast<char*>(&As[nxt][0]) + awoff[i]) = h4;
            }
            asm volatile("s_waitcnt lgkmcnt(0)" ::: "memory");
            __builtin_amdgcn_s_barrier();          // As[nxt] ready; As[cur] reads done
        }
    }

    // epilogue: s[row] = sum_h tanh(C[row][h] + qp[b][h]) * wv[h]   (verified layout)
    if (tid < BM) s_rows[tid] = 0.f;
    __syncthreads();

    float qv[4], wvv[4];
    #pragma unroll
    for (int j = 0; j < 4; ++j) {
        int col = wid * 64 + j * 16 + l15;        // C/D: col = lane&15 (+16*j frag)
        qv[j]  = qp[b * HDIM + col];
        wvv[j] = wv[col];
    }
    #pragma unroll
    for (int i = 0; i < 4; ++i) {
        #pragma unroll
        for (int r = 0; r < 4; ++r) {
            float p = 0.f;
            #pragma unroll
            for (int j = 0; j < 4; ++j) {
                float x = acc[i][j][r] + qv[j];
                p += tanh_fast(x) * wvv[j];
            }
            p += __shfl_xor(p, 1);
            p += __shfl_xor(p, 2);
            p += __shfl_xor(p, 4);
            p += __shfl_xor(p, 8);
            if (l15 == 0)                         // C/D: row = (lane>>4)*4 + reg
                atomicAdd(&s_rows[i * 16 + l4 * 4 + r], p);
        }
    }
    __syncthreads();
    if (tid < BM) scores[row0 + tid] = s_rows[tid];
}

// ---- Kernel 2: per-batch softmax over 4096 scores, multiply by values ----
__global__ void k_softmax(const float* __restrict__ scores, const float* __restrict__ values,
                          float* __restrict__ out) {
    __shared__ float red[32];
    const int b = blockIdx.x, tid = threadIdx.x;  // 1024 threads, 16 waves
    const float* s = scores + b * NKEYS;
    float v[4];
    float m = -1e30f;
    #pragma unroll
    for (int i = 0; i < 4; ++i) { v[i] = s[tid + i * 1024]; m = fmaxf(m, v[i]); }
    #pragma unroll
    for (int off = 1; off < 64; off <<= 1) m = fmaxf(m, __shfl_xor(m, off));
    const int w = tid >> 6;
    if ((tid & 63) == 0) red[w] = m;
    __syncthreads();
    m = red[0];
    #pragma unroll
    for (int i = 1; i < 16; ++i) m = fmaxf(m, red[i]);
    float sum = 0.f;
    #pragma unroll
    for (int i = 0; i < 4; ++i) { v[i] = __expf(v[i] - m); sum += v[i]; }
    #pragma unroll
    for (int off = 1; off < 64; off <<= 1) sum += __shfl_xor(sum, off);
    if ((tid & 63) == 0) red[16 + w] = sum;
    __syncthreads();
    sum = red[16];
    #pragma unroll
    for (int i = 1; i < 16; ++i) sum += red[16 + i];
    const float inv = 1.0f / sum;
    #pragma unroll
    for (int i = 0; i < 4; ++i) {
        int n = tid + i * 1024;
        out[b * NKEYS + n] = v[i] * inv * values[b * NKEYS + n];
    }
}

extern "C" void kernel_launch(void* const* d_in, const int* in_sizes, int n_in,
                              void* d_out, int out_size, void* d_ws, size_t ws_size,
                              hipStream_t stream) {
    const float* queries = (const float*)d_in[0];
    const float* keys    = (const float*)d_in[1];
    const float* values  = (const float*)d_in[2];
    const float* Wq      = (const float*)d_in[3];
    const float* Wk      = (const float*)d_in[4];
    const float* wv      = (const float*)d_in[5];
    float* out = (float*)d_out;

    char* ws = (char*)d_ws;
    float* scores        = (float*)ws;                                   // 512 KB
    float* qp            = (float*)(ws + 131072 * 4);                    //  32 KB
    unsigned short* WkT  = (unsigned short*)(ws + 131072 * 4 + 8192 * 4);// 256 KB

    hipLaunchKernelGGL(k_prep_wkT, dim3(32),   dim3(256),  0, stream, Wk, WkT);
    hipLaunchKernelGGL(k_qproj,    dim3(128),  dim3(256),  0, stream, queries, Wq, qp);
    hipLaunchKernelGGL(k_scores,   dim3(NB * NKEYS / BM), dim3(256), 0, stream,
                       keys, WkT, qp, wv, scores);
    hipLaunchKernelGGL(k_softmax,  dim3(NB),   dim3(1024), 0, stream, scores, values, out);
}